// Round 3
// baseline (55.330 us; speedup 1.0000x reference)
//
#include <hip/hip_runtime.h>
#include <math.h>

#define B_   64
#define O_   512
#define N_   784
#define NCH  16
#define CHJ  49            // NCH * CHJ == N_
#define BIGV 1e10f

#define RANK_BLOCKS   (B_ * 4)                    // 64 rows x 4 chunks of 196
#define TRANS_BLOCKS  ((O_ * N_) / 256)           // 1568
#define CHUNK_I       196

// ---------------------------------------------------------------------------
// Kernel 1 (fused): stable argsort via rank/counting sort  +  w transpose.
//   rank(i) = #{k : e[k]<e[i] || (e[k]==e[i] && k<i)}  == stable argsort perm.
//   Barrier-free, all CUs busy. Transpose blocks ride along in the same grid.
// ---------------------------------------------------------------------------
__global__ __launch_bounds__(256) void snn_rank_trans(const float* __restrict__ x,
                                                      const float* __restrict__ w,
                                                      float* __restrict__ s_out,
                                                      int* __restrict__ i_out,
                                                      float* __restrict__ wT)
{
    int bid = blockIdx.x;
    if (bid >= RANK_BLOCKS) {
        // -------- transpose part: wT[n][o] = w[o][n] --------
        int t = (bid - RANK_BLOCKS) * 256 + threadIdx.x;   // t indexes wT[N][O]
        int n = t >> 9;            // / O_
        int o = t & (O_ - 1);      // % O_
        wT[t] = w[o * N_ + n];     // coalesced write; strided read (L2-resident)
        return;
    }

    // -------- rank part --------
    __shared__ float se[N_];       // e row (float4-readable: N_ % 4 == 0)
    const int b     = bid >> 2;
    const int chunk = bid & 3;

    for (int i = threadIdx.x; i < N_; i += 256)
        se[i] = expf(x[b * N_ + i] * 1.79f);
    __syncthreads();

    if (threadIdx.x < CHUNK_I) {
        const int i  = chunk * CHUNK_I + threadIdx.x;
        const float ei = se[i];
        int r = 0;
        const float4* se4 = (const float4*)se;
        #pragma unroll 4
        for (int k4 = 0; k4 < N_ / 4; ++k4) {
            float4 v = se4[k4];    // LDS broadcast: all lanes same addr, no conflict
            int k = k4 * 4;
            r += (v.x < ei || (v.x == ei && (k + 0) < i)) ? 1 : 0;
            r += (v.y < ei || (v.y == ei && (k + 1) < i)) ? 1 : 0;
            r += (v.z < ei || (v.z == ei && (k + 2) < i)) ? 1 : 0;
            r += (v.w < ei || (v.w == ei && (k + 3) < i)) ? 1 : 0;
        }
        s_out[b * N_ + r] = ei;    // ranks are a bijection -> scatter is exact
        i_out[b * N_ + r] = i;
    }
}

// ---------------------------------------------------------------------------
// Kernel 2: partial first-hit scan over a j-chunk of CHJ.
// cond[j] = (wim/den < s[j-1]) && (ws > 1), div-free as wim < s[j-1]*den
// (den > 0 after clip). Store (num, den) of first hit; den==0 => none.
// ---------------------------------------------------------------------------
__global__ __launch_bounds__(256) void snn_part(const float* __restrict__ wT,
                                                const float* __restrict__ s_in,
                                                const int*  __restrict__ i_in,
                                                float* __restrict__ pnum,
                                                float* __restrict__ pden)
{
    __shared__ float lls[CHJ + 1];
    __shared__ int   lli[CHJ + 1];
    const int b  = blockIdx.x;
    const int c  = blockIdx.z;
    const int o  = blockIdx.y * 256 + threadIdx.x;
    const int j0 = c * CHJ;

    // stage global j in [j0-1, j0+CHJ-1] at local k = j - j0 + 1
    if (threadIdx.x <= CHJ) {
        int gj = j0 - 1 + threadIdx.x;
        if (gj >= 0) {
            lls[threadIdx.x] = s_in[b * N_ + gj];
            lli[threadIdx.x] = i_in[b * N_ + gj];
        }
    }
    __syncthreads();

    float wprev, mulprev;
    float fnum = 0.0f, fden = 0.0f;
    bool  fnd = false;
    int   jstart;

    if (c == 0) {
        // j = 0: ws_sum = w0, inp_shift = +inf  (cond1 true for finite mul0)
        float w0   = wT[lli[1] * O_ + o];
        float s0   = lls[1];
        float mul0 = s0 * w0;
        float den0 = fminf(fmaxf(w0 - 1.0f, 1e-10f), BIGV);
        bool cond = (mul0 < INFINITY) && (w0 > 1.0f);
        if (cond) { fnum = mul0; fden = den0; fnd = true; }
        wprev = w0; mulprev = mul0;
        jstart = 1;
    } else {
        wprev   = wT[lli[0] * O_ + o];
        mulprev = lls[0] * wprev;
        jstart  = j0;
    }

    #pragma unroll 4
    for (int j = jstart; j < j0 + CHJ; ++j) {
        int   k     = j - j0 + 1;
        float wj    = wT[lli[k] * O_ + o];
        float sj    = lls[k];
        float shift = lls[k - 1];          // inp_shift[j] = s[j-1]
        float mulj  = sj * wj;
        float ws    = wj + wprev;
        float wim   = mulj + mulprev;
        float den   = fminf(fmaxf(ws - 1.0f, 1e-10f), BIGV);
        bool cond   = (wim < shift * den) && (ws > 1.0f);
        if (cond && !fnd) { fnum = wim; fden = den; fnd = true; }
        wprev = wj; mulprev = mulj;
    }

    int t = b * O_ + o;
    pnum[c * (B_ * O_) + t] = fnum;
    pden[c * (B_ * O_) + t] = fden;        // 0 iff not found (found den >= 1e-10)
}

// ---------------------------------------------------------------------------
// Kernel 3: combine chunk results per (b,o): first chunk with den>0 wins;
// else j=N tail (BIG if BIG < s[N-1]); else default out_all[0].
// ---------------------------------------------------------------------------
__global__ __launch_bounds__(256) void snn_combine(const float* __restrict__ wT,
                                                   const float* __restrict__ s_in,
                                                   const int*  __restrict__ i_in,
                                                   const float* __restrict__ pnum,
                                                   const float* __restrict__ pden,
                                                   float* __restrict__ out)
{
    int t = blockIdx.x * 256 + threadIdx.x;
    if (t >= B_ * O_) return;
    int b = t >> 9;            // / O_
    int o = t & (O_ - 1);

    float num = 0.0f, den = 0.0f;
    bool fnd = false;
    #pragma unroll
    for (int c = 0; c < NCH; ++c) {
        float pd = pden[c * (B_ * O_) + t];
        if (!fnd && pd > 0.0f) {
            num = pnum[c * (B_ * O_) + t];
            den = pd;
            fnd = true;
        }
    }

    float res;
    if (fnd) {
        res = num / den;
    } else {
        float slast = s_in[b * N_ + N_ - 1];
        if (BIGV < slast) {
            res = BIGV;                         // j = N hit
        } else {
            int   li0  = i_in[b * N_];          // default: out_all[0]
            float w0   = wT[li0 * O_ + o];
            float mul0 = s_in[b * N_] * w0;
            float d0   = fminf(fmaxf(w0 - 1.0f, 1e-10f), BIGV);
            res = mul0 / d0;
        }
    }
    out[t] = res;
}

extern "C" void kernel_launch(void* const* d_in, const int* in_sizes, int n_in,
                              void* d_out, int out_size, void* d_ws, size_t ws_size,
                              hipStream_t stream)
{
    const float* x = (const float*)d_in[0];   // [B, N]
    const float* w = (const float*)d_in[1];   // [O, N]
    float* out = (float*)d_out;               // [B, O]

    char* ws = (char*)d_ws;
    size_t off = 0;
    float* wT   = (float*)(ws + off); off += (size_t)N_ * O_ * sizeof(float);
    float* s    = (float*)(ws + off); off += (size_t)B_ * N_ * sizeof(float);
    int*   ix   = (int*)  (ws + off); off += (size_t)B_ * N_ * sizeof(int);
    float* pnum = (float*)(ws + off); off += (size_t)NCH * B_ * O_ * sizeof(float);
    float* pden = (float*)(ws + off); off += (size_t)NCH * B_ * O_ * sizeof(float);

    hipLaunchKernelGGL(snn_rank_trans, dim3(RANK_BLOCKS + TRANS_BLOCKS), dim3(256),
                       0, stream, x, w, s, ix, wT);

    hipLaunchKernelGGL(snn_part, dim3(B_, O_ / 256, NCH), dim3(256), 0, stream,
                       wT, s, ix, pnum, pden);

    hipLaunchKernelGGL(snn_combine, dim3((B_ * O_ + 255) / 256), dim3(256), 0, stream,
                       wT, s, ix, pnum, pden, out);
}